// Round 4
// baseline (1276.966 us; speedup 1.0000x reference)
//
#include <hip/hip_runtime.h>
#include <stdint.h>

#define HEADS 12
#define HD 32
#define NTOK 49
#define DIM 384
#define SCALE 0.17677669529663687f

typedef __attribute__((ext_vector_type(8))) short s8v;   // 8 bf16 (4 VGPRs) MFMA A/B frag
typedef __attribute__((ext_vector_type(4))) float f4v;   // MFMA C/D frag

__device__ __forceinline__ unsigned short f2bf(float f) {
    union { float f; unsigned int i; } c; c.f = f;
    unsigned int x = c.i;
    return (unsigned short)((x + 0x7FFFu + ((x >> 16) & 1u)) >> 16);
}

// load 8 consecutive fp32 (32B, 16B-aligned) -> bf16x8 fragment
__device__ __forceinline__ s8v load_pack8(const float* p) {
    float4 a = *(const float4*)p;
    float4 b = *(const float4*)(p + 4);
    s8v r;
    r[0] = (short)f2bf(a.x); r[1] = (short)f2bf(a.y);
    r[2] = (short)f2bf(a.z); r[3] = (short)f2bf(a.w);
    r[4] = (short)f2bf(b.x); r[5] = (short)f2bf(b.y);
    r[6] = (short)f2bf(b.z); r[7] = (short)f2bf(b.w);
    return r;
}

// ---- launch-constant weight fragments, prepacked bf16 in MFMA lane order ----
// qpack: [h][ks][nt][lane] -> B-frag for qkv GEMM (q section prescaled by SCALE)
//        head stride = 12*6*64 frags = 73728 B (contiguous => LDS-stageable by memcpy)
// ppack: [h][ct][lane]     -> B-frag for proj GEMM (ct = col-tile 0..23)
#define QFRAGS (12 * 12 * 6 * 64)   // 55296
#define PFRAGS (12 * 24 * 64)       // 18432
__device__ s8v qpack_g[QFRAGS];
__device__ s8v ppack_g[PFRAGS];

__global__ __launch_bounds__(256) void prepack(
    const float* __restrict__ qkvw, const float* __restrict__ projw)
{
    int t = blockIdx.x * 256 + threadIdx.x;
    if (t < QFRAGS) {
        int lane = t & 63, fid = t >> 6;
        int nt = fid % 6, ks = (fid / 6) % 12, h = fid / 72;
        int l15 = lane & 15, lq = lane >> 4;
        int c96 = nt * 16 + l15;
        int sect = c96 >> 5, cc = c96 & 31;
        const float* src = qkvw + (size_t)(sect * DIM + h * HD + cc) * DIM + ks * 32 + lq * 8;
        float s = (sect == 0) ? SCALE : 1.0f;
        float4 a = *(const float4*)src;
        float4 b = *(const float4*)(src + 4);
        s8v r;
        r[0] = (short)f2bf(a.x * s); r[1] = (short)f2bf(a.y * s);
        r[2] = (short)f2bf(a.z * s); r[3] = (short)f2bf(a.w * s);
        r[4] = (short)f2bf(b.x * s); r[5] = (short)f2bf(b.y * s);
        r[6] = (short)f2bf(b.z * s); r[7] = (short)f2bf(b.w * s);
        qpack_g[t] = r;
    } else if (t < QFRAGS + PFRAGS) {
        int u = t - QFRAGS;
        int lane = u & 63, fid = u >> 6;
        int ct = fid % 24, h = fid / 24;
        int l15 = lane & 15, lq = lane >> 4;
        const float* src = projw + (size_t)(ct * 16 + l15) * DIM + h * HD + lq * 8;
        ppack_g[u] = load_pack8(src);
    }
}

// LDS layout (ushort units), 60928 B total (< 64 KB static limit):
//   QK:   [2][64 tokens][40 (32+8 pad)]           = 5120
//   VT:   v^T [32 d][72 (64+8 pad) tokens]        = 2304
//   PL:   P [64][72]; ho reuses cols [0,32) after  = 4608
//   WB:   2 x 3-ks weight-frag chunk buffers (18 frags x 1KB each)
#define QK_OFF 0
#define VT_OFF 5120
#define PL_OFF 7424
#define WB_OFF 12032                 // ushorts; each buf = 9216 ushorts (18432 B)
#define LDS_TOT (12032 + 2 * 9216)   // 30464 ushorts = 60928 B

// async global->LDS: one 1KB wave-instr per i (wave-uniform LDS base + lane*16)
__device__ __forceinline__ void stage18(const char* g, char* lbase, int w, int l) {
    for (int i = w; i < 18; i += 4)
        __builtin_amdgcn_global_load_lds(
            (const __attribute__((address_space(1))) void*)(g + i * 1024 + l * 16),
            (__attribute__((address_space(3))) void*)(lbase + i * 1024),
            16, 0, 0);
}

__device__ __forceinline__ void chunkA(const unsigned short* fb0, const s8v* xa,
                                       int k0, f4v* acc) {
#pragma unroll
    for (int ksl = 0; ksl < 3; ++ksl) {
        s8v a = xa[k0 + ksl];
        const unsigned short* fb = fb0 + ksl * 3072;
#pragma unroll
        for (int nt = 0; nt < 6; ++nt)
            acc[nt] = __builtin_amdgcn_mfma_f32_16x16x32_bf16(
                a, *(const s8v*)(fb + nt * 512), acc[nt], 0, 0, 0);
    }
}

__global__ __launch_bounds__(256, 2) void winattn_fused(
    const float* __restrict__ xg,              // [B,49,384] fp32
    const unsigned char* __restrict__ maskg,   // [64,49,49] bool
    const float* __restrict__ qkvb,            // [1152] fp32
    const float* __restrict__ projb,           // [384] fp32
    const float* __restrict__ rpb,             // [169,12] fp32
    const int*   __restrict__ relidx,          // [49,49] int32
    float*       __restrict__ outg)            // [B,49,384] fp32
{
    __shared__ __align__(16) unsigned short lds[LDS_TOT];
    const int tid = threadIdx.x;
    const int w   = tid >> 6;     // wave 0..3
    const int l   = tid & 63;
    const int l15 = l & 15;
    const int lq  = l >> 4;       // 0..3
    const int b   = blockIdx.x;

    const float*         xw    = xg + (size_t)b * (NTOK * DIM);
    const unsigned char* maskw = maskg + (size_t)(b & 63) * (NTOK * NTOK);
    char* const wb0 = (char*)lds + (WB_OFF * 2);          // byte base of chunk bufs

    // ---- x A-fragments: row fixed per lane for whole kernel (pad rows clamp to 48)
    const int arow = min(w * 16 + l15, NTOK - 1);
    s8v xa[12];
#pragma unroll
    for (int ks = 0; ks < 12; ++ks)
        xa[ks] = load_pack8(xw + arow * DIM + ks * 32 + lq * 8);

    // ---- bias byte-offsets into rpb rows; -1 sentinel => score := -1e30
    int boff[4][4];
#pragma unroll
    for (int nt = 0; nt < 4; ++nt)
#pragma unroll
        for (int reg = 0; reg < 4; ++reg) {
            int i = w * 16 + lq * 4 + reg;     // score row (query token)
            int j = nt * 16 + l15;             // score col (key token)
            if (i < NTOK && j < NTOK)
                boff[nt][reg] = maskw[i * NTOK + j] ? -1 : relidx[i * NTOK + j] * (HEADS * 4);
            else
                boff[nt][reg] = (j >= NTOK) ? -1 : 0;
        }

    const f4v fz = {0.f, 0.f, 0.f, 0.f};
    f4v oc[4][6];                               // persistent out accumulator
#pragma unroll
    for (int mt = 0; mt < 4; ++mt)
#pragma unroll
        for (int j = 0; j < 6; ++j) oc[mt][j] = fz;

    // prologue: stage head-0 chunk-0 into buf0
    stage18((const char*)qpack_g, wb0, w, l);

    for (int h = 0; h < HEADS; ++h) {
        const char* wsrc = (const char*)qpack_g + (size_t)h * 73728;
        const unsigned short* fbl = &lds[WB_OFF] + l * 8;   // lane frag base (buf0)

        __syncthreads();   // A-entry: drains c0 staging; prev head's LDS reads all done

        f4v acc[6];
#pragma unroll
        for (int nt = 0; nt < 6; ++nt) acc[nt] = fz;

        // chunk 0 (buf0): prefetch c1 -> buf1
        stage18(wsrc + 18432, wb0 + 18432, w, l);
        chunkA(fbl, xa, 0, acc);
        __syncthreads();
        // chunk 1 (buf1): prefetch c2 -> buf0
        stage18(wsrc + 2 * 18432, wb0, w, l);
        chunkA(fbl + 9216, xa, 3, acc);
        __syncthreads();
        // chunk 2 (buf0): prefetch c3 -> buf1
        stage18(wsrc + 3 * 18432, wb0 + 18432, w, l);
        chunkA(fbl, xa, 6, acc);
        __syncthreads();
        // chunk 3 (buf1): prefetch NEXT head's c0 -> buf0
        if (h < HEADS - 1)
            stage18(wsrc + 73728, wb0, w, l);
        chunkA(fbl + 9216, xa, 9, acc);

        // epilogue: +bias; q,k -> QK; v -> VT (transposed)
#pragma unroll
        for (int nt = 0; nt < 6; ++nt) {
            int c96 = nt * 16 + l15;
            int sect = c96 >> 5;                // 0=q 1=k 2=v
            int cc = c96 & 31;
            float bias = qkvb[sect * DIM + h * HD + cc];
            if (sect == 0) bias *= SCALE;
#pragma unroll
            for (int reg = 0; reg < 4; ++reg) {
                int row = w * 16 + lq * 4 + reg;
                float v = acc[nt][reg] + bias;
                unsigned short bv = f2bf(v);
                if (sect < 2) lds[QK_OFF + sect * 2560 + row * 40 + cc] = bv;
                else          lds[VT_OFF + cc * 72 + row] = bv;
            }
        }
        __syncthreads();   // B2: q,k,v visible cross-wave

        // ======== Phase B: scores, bias, mask, softmax in regs ========
        s8v qa = *(const s8v*)(&lds[QK_OFF + (w * 16 + l15) * 40 + lq * 8]);
        f4v sc[4];
#pragma unroll
        for (int nt = 0; nt < 4; ++nt) {
            s8v kb = *(const s8v*)(&lds[QK_OFF + 2560 + (nt * 16 + l15) * 40 + lq * 8]);
            sc[nt] = __builtin_amdgcn_mfma_f32_16x16x32_bf16(qa, kb, fz, 0, 0, 0);
        }
        const char* rpbb = (const char*)rpb + h * 4;
#pragma unroll
        for (int nt = 0; nt < 4; ++nt)
#pragma unroll
            for (int reg = 0; reg < 4; ++reg) {
                int bo = boff[nt][reg];
                float v = sc[nt][reg] + *(const float*)(rpbb + (bo < 0 ? 0 : bo));
                sc[nt][reg] = (bo < 0) ? -1e30f : v;
            }
#pragma unroll
        for (int reg = 0; reg < 4; ++reg) {
            float m = fmaxf(fmaxf(sc[0][reg], sc[1][reg]), fmaxf(sc[2][reg], sc[3][reg]));
            m = fmaxf(m, __shfl_xor(m, 1));
            m = fmaxf(m, __shfl_xor(m, 2));
            m = fmaxf(m, __shfl_xor(m, 4));
            m = fmaxf(m, __shfl_xor(m, 8));
            float e0 = __expf(sc[0][reg] - m);
            float e1 = __expf(sc[1][reg] - m);
            float e2 = __expf(sc[2][reg] - m);
            float e3 = __expf(sc[3][reg] - m);
            float t = (e0 + e1) + (e2 + e3);
            t += __shfl_xor(t, 1);
            t += __shfl_xor(t, 2);
            t += __shfl_xor(t, 4);
            t += __shfl_xor(t, 8);
            float inv = 1.0f / t;
            sc[0][reg] = e0 * inv; sc[1][reg] = e1 * inv;
            sc[2][reg] = e2 * inv; sc[3][reg] = e3 * inv;
        }
        // P -> PL (own rows only; same-wave round trip, no barrier needed)
#pragma unroll
        for (int nt = 0; nt < 4; ++nt)
#pragma unroll
            for (int reg = 0; reg < 4; ++reg) {
                int row = w * 16 + lq * 4 + reg;
                lds[PL_OFF + row * 72 + nt * 16 + l15] = f2bf(sc[nt][reg]);
            }

        // ======== Phase C: head_out = P @ V  (M=16/wave, N=32, K=64) ========
        f4v ho[2] = {fz, fz};
#pragma unroll
        for (int ks = 0; ks < 2; ++ks) {
            s8v pa = *(const s8v*)(&lds[PL_OFF + (w * 16 + l15) * 72 + ks * 32 + lq * 8]);
#pragma unroll
            for (int nt = 0; nt < 2; ++nt) {
                s8v vb = *(const s8v*)(&lds[VT_OFF + (nt * 16 + l15) * 72 + ks * 32 + lq * 8]);
                ho[nt] = __builtin_amdgcn_mfma_f32_16x16x32_bf16(pa, vb, ho[nt], 0, 0, 0);
            }
        }
        // ho -> PL cols [0,32) of own rows (data-dependence-safe; cross-wave via B3)
#pragma unroll
        for (int nt = 0; nt < 2; ++nt)
#pragma unroll
            for (int reg = 0; reg < 4; ++reg) {
                int row = w * 16 + lq * 4 + reg;
                lds[PL_OFF + row * 72 + nt * 16 + l15] = f2bf(ho[nt][reg]);
            }
        __syncthreads();   // B3: ho visible cross-wave

        // ======== Phase D: out += head_out @ proj_w[:, h*32:+32]^T ========
        s8v ha[4];
#pragma unroll
        for (int mt = 0; mt < 4; ++mt)
            ha[mt] = *(const s8v*)(&lds[PL_OFF + (mt * 16 + l15) * 72 + lq * 8]);
        const s8v* pp = ppack_g + (size_t)h * (24 * 64) + l;
#pragma unroll
        for (int j = 0; j < 6; ++j) {
            s8v pbj = pp[(w * 6 + j) * 64];
#pragma unroll
            for (int mt = 0; mt < 4; ++mt)
                oc[mt][j] = __builtin_amdgcn_mfma_f32_16x16x32_bf16(ha[mt], pbj, oc[mt][j], 0, 0, 0);
        }
    }

    // ======== epilogue: + proj_b, store fp32 (rows < 49) ========
#pragma unroll
    for (int j = 0; j < 6; ++j) {
        int col = (w * 6 + j) * 16 + l15;
        float pbv = projb[col];
#pragma unroll
        for (int mt = 0; mt < 4; ++mt)
#pragma unroll
            for (int reg = 0; reg < 4; ++reg) {
                int row = mt * 16 + lq * 4 + reg;
                if (row < NTOK)
                    outg[(size_t)b * (NTOK * DIM) + row * DIM + col] =
                        oc[mt][j][reg] + pbv;
            }
    }
}

extern "C" void kernel_launch(void* const* d_in, const int* in_sizes, int n_in,
                              void* d_out, int out_size, void* d_ws, size_t ws_size,
                              hipStream_t stream) {
    (void)n_in; (void)d_ws; (void)ws_size; (void)out_size;
    const int B = in_sizes[0] / (NTOK * DIM);   // in_sizes is ELEMENT count -> B = 2048
    hipLaunchKernelGGL(prepack, dim3((QFRAGS + PFRAGS) / 256), dim3(256), 0, stream,
        (const float*)d_in[2],     // qkv_w
        (const float*)d_in[4]);    // proj_w
    hipLaunchKernelGGL(winattn_fused, dim3(B), dim3(256), 0, stream,
        (const float*)        d_in[0],
        (const unsigned char*)d_in[1],
        (const float*)        d_in[3],   // qkv_b
        (const float*)        d_in[5],   // proj_b
        (const float*)        d_in[6],   // rpb_table
        (const int*)          d_in[7],   // rel_index
        (float*)              d_out);
}

// Round 6
// 1082.725 us; speedup vs baseline: 1.1794x; 1.1794x over previous
//
#include <hip/hip_runtime.h>
#include <stdint.h>

#define HEADS 12
#define HD 32
#define NTOK 49
#define DIM 384
#define SCALE 0.17677669529663687f

typedef __attribute__((ext_vector_type(8))) short s8v;   // 8 bf16 (4 VGPRs) MFMA A/B frag
typedef __attribute__((ext_vector_type(4))) float f4v;   // MFMA C/D frag
typedef __attribute__((ext_vector_type(4))) float f4n;   // native vec4 for NT loads

__device__ __forceinline__ unsigned short f2bf(float f) {
    union { float f; unsigned int i; } c; c.f = f;
    unsigned int x = c.i;
    return (unsigned short)((x + 0x7FFFu + ((x >> 16) & 1u)) >> 16);
}

// load 8 consecutive fp32 (32B, 16B-aligned) -> bf16x8 fragment
__device__ __forceinline__ s8v load_pack8(const float* p) {
    float4 a = *(const float4*)p;
    float4 b = *(const float4*)(p + 4);
    s8v r;
    r[0] = (short)f2bf(a.x); r[1] = (short)f2bf(a.y);
    r[2] = (short)f2bf(a.z); r[3] = (short)f2bf(a.w);
    r[4] = (short)f2bf(b.x); r[5] = (short)f2bf(b.y);
    r[6] = (short)f2bf(b.z); r[7] = (short)f2bf(b.w);
    return r;
}

// non-temporal variant for STREAMING x (don't let it evict weights from L2)
__device__ __forceinline__ s8v load_pack8_nt(const float* p) {
    f4n a = __builtin_nontemporal_load((const f4n*)p);
    f4n b = __builtin_nontemporal_load((const f4n*)(p + 4));
    s8v r;
    r[0] = (short)f2bf(a[0]); r[1] = (short)f2bf(a[1]);
    r[2] = (short)f2bf(a[2]); r[3] = (short)f2bf(a[3]);
    r[4] = (short)f2bf(b[0]); r[5] = (short)f2bf(b[1]);
    r[6] = (short)f2bf(b[2]); r[7] = (short)f2bf(b[3]);
    return r;
}

// ---- launch-constant weight fragments, prepacked bf16 in MFMA lane order ----
// qpack: [h][ks][nt][lane] -> B-frag for qkv GEMM (q section prescaled by SCALE)
//        head stride = 12*6*64 frags = 73728 B (contiguous => LDS-stageable by memcpy)
// ppack: [h][ct][lane]     -> B-frag for proj GEMM (ct = col-tile 0..23)
#define QFRAGS (12 * 12 * 6 * 64)   // 55296
#define PFRAGS (12 * 24 * 64)       // 18432
__device__ s8v qpack_g[QFRAGS];
__device__ s8v ppack_g[PFRAGS];

__global__ __launch_bounds__(256) void prepack(
    const float* __restrict__ qkvw, const float* __restrict__ projw)
{
    int t = blockIdx.x * 256 + threadIdx.x;
    if (t < QFRAGS) {
        int lane = t & 63, fid = t >> 6;
        int nt = fid % 6, ks = (fid / 6) % 12, h = fid / 72;
        int l15 = lane & 15, lq = lane >> 4;
        int c96 = nt * 16 + l15;
        int sect = c96 >> 5, cc = c96 & 31;
        const float* src = qkvw + (size_t)(sect * DIM + h * HD + cc) * DIM + ks * 32 + lq * 8;
        float s = (sect == 0) ? SCALE : 1.0f;
        float4 a = *(const float4*)src;
        float4 b = *(const float4*)(src + 4);
        s8v r;
        r[0] = (short)f2bf(a.x * s); r[1] = (short)f2bf(a.y * s);
        r[2] = (short)f2bf(a.z * s); r[3] = (short)f2bf(a.w * s);
        r[4] = (short)f2bf(b.x * s); r[5] = (short)f2bf(b.y * s);
        r[6] = (short)f2bf(b.z * s); r[7] = (short)f2bf(b.w * s);
        qpack_g[t] = r;
    } else if (t < QFRAGS + PFRAGS) {
        int u = t - QFRAGS;
        int lane = u & 63, fid = u >> 6;
        int ct = fid % 24, h = fid / 24;
        int l15 = lane & 15, lq = lane >> 4;
        const float* src = projw + (size_t)(ct * 16 + l15) * DIM + h * HD + lq * 8;
        ppack_g[u] = load_pack8(src);
    }
}

// LDS layout (ushort units), 60928 B total (< 64 KB static limit):
//   QK:   [2][64 tokens][40 (32+8 pad)]           = 5120
//   VT:   v^T [32 d][72 (64+8 pad) tokens]        = 2304
//   PL:   P [64][72]; ho reuses cols [0,32) after  = 4608
//   WB:   2 x 3-ks weight-frag chunk buffers (18 frags x 1KB each)
#define QK_OFF 0
#define VT_OFF 5120
#define PL_OFF 7424
#define WB_OFF 12032                 // ushorts; each buf = 9216 ushorts (18432 B)
#define LDS_TOT (12032 + 2 * 9216)   // 30464 ushorts = 60928 B

// async global->LDS: one 1KB wave-instr per i (wave-uniform LDS base + lane*16)
__device__ __forceinline__ void stage18(const char* g, char* lbase, int w, int l) {
    for (int i = w; i < 18; i += 4)
        __builtin_amdgcn_global_load_lds(
            (const __attribute__((address_space(1))) void*)(g + i * 1024 + l * 16),
            (__attribute__((address_space(3))) void*)(lbase + i * 1024),
            16, 0, 0);
}

__device__ __forceinline__ void chunkA(const unsigned short* fb0, const s8v* xa,
                                       int k0, f4v* acc) {
#pragma unroll
    for (int ksl = 0; ksl < 3; ++ksl) {
        s8v a = xa[k0 + ksl];
        const unsigned short* fb = fb0 + ksl * 3072;
#pragma unroll
        for (int nt = 0; nt < 6; ++nt)
            acc[nt] = __builtin_amdgcn_mfma_f32_16x16x32_bf16(
                a, *(const s8v*)(fb + nt * 512), acc[nt], 0, 0, 0);
    }
}

__global__ __launch_bounds__(256, 2) void winattn_fused(
    const float* __restrict__ xg,              // [B,49,384] fp32
    const unsigned char* __restrict__ maskg,   // [64,49,49] bool
    const float* __restrict__ qkvb,            // [1152] fp32
    const float* __restrict__ projb,           // [384] fp32
    const float* __restrict__ rpb,             // [169,12] fp32
    const int*   __restrict__ relidx,          // [49,49] int32
    float*       __restrict__ outg)            // [B,49,384] fp32
{
    __shared__ __align__(16) unsigned short lds[LDS_TOT];
    const int tid = threadIdx.x;
    const int w   = tid >> 6;     // wave 0..3
    const int l   = tid & 63;
    const int l15 = l & 15;
    const int lq  = l >> 4;       // 0..3
    const int b   = blockIdx.x;

    const float*         xw    = xg + (size_t)b * (NTOK * DIM);
    const unsigned char* maskw = maskg + (size_t)(b & 63) * (NTOK * NTOK);
    char* const wb0 = (char*)lds + (WB_OFF * 2);          // byte base of chunk bufs

    // ---- x A-fragments (non-temporal: streaming, read once per block)
    const int arow = min(w * 16 + l15, NTOK - 1);
    s8v xa[12];
#pragma unroll
    for (int ks = 0; ks < 12; ++ks)
        xa[ks] = load_pack8_nt(xw + arow * DIM + ks * 32 + lq * 8);

    // ---- bias byte-offsets into rpb rows; -1 sentinel => score := -1e30
    int boff[4][4];
#pragma unroll
    for (int nt = 0; nt < 4; ++nt)
#pragma unroll
        for (int reg = 0; reg < 4; ++reg) {
            int i = w * 16 + lq * 4 + reg;     // score row (query token)
            int j = nt * 16 + l15;             // score col (key token)
            if (i < NTOK && j < NTOK)
                boff[nt][reg] = maskw[i * NTOK + j] ? -1 : relidx[i * NTOK + j] * (HEADS * 4);
            else
                boff[nt][reg] = (j >= NTOK) ? -1 : 0;
        }

    const f4v fz = {0.f, 0.f, 0.f, 0.f};
    f4v oc[4][6];                               // persistent out accumulator
#pragma unroll
    for (int mt = 0; mt < 4; ++mt)
#pragma unroll
        for (int j = 0; j < 6; ++j) oc[mt][j] = fz;

    // prologue: stage head-0 chunk-0 into buf0
    stage18((const char*)qpack_g, wb0, w, l);

    for (int h = 0; h < HEADS; ++h) {
        const char* wsrc = (const char*)qpack_g + (size_t)h * 73728;
        const unsigned short* fbl = &lds[WB_OFF] + l * 8;   // lane frag base (buf0)

        __syncthreads();   // A-entry: drains c0 staging; prev head's LDS reads all done

        f4v acc[6];
#pragma unroll
        for (int nt = 0; nt < 6; ++nt) acc[nt] = fz;

        // chunk 0 (buf0): prefetch c1 -> buf1
        stage18(wsrc + 18432, wb0 + 18432, w, l);
        chunkA(fbl, xa, 0, acc);
        __syncthreads();
        // chunk 1 (buf1): prefetch c2 -> buf0
        stage18(wsrc + 2 * 18432, wb0, w, l);
        chunkA(fbl + 9216, xa, 3, acc);
        __syncthreads();
        // chunk 2 (buf0): prefetch c3 -> buf1
        stage18(wsrc + 3 * 18432, wb0 + 18432, w, l);
        chunkA(fbl, xa, 6, acc);
        __syncthreads();
        // chunk 3 (buf1): prefetch NEXT head's c0 -> buf0 (hides under B/C/D)
        if (h < HEADS - 1)
            stage18(wsrc + 73728, wb0, w, l);
        chunkA(fbl + 9216, xa, 9, acc);

        // epilogue: +bias; q,k -> QK; v -> VT (transposed)
#pragma unroll
        for (int nt = 0; nt < 6; ++nt) {
            int c96 = nt * 16 + l15;
            int sect = c96 >> 5;                // 0=q 1=k 2=v
            int cc = c96 & 31;
            float bias = qkvb[sect * DIM + h * HD + cc];
            if (sect == 0) bias *= SCALE;
#pragma unroll
            for (int reg = 0; reg < 4; ++reg) {
                int row = w * 16 + lq * 4 + reg;
                float v = acc[nt][reg] + bias;
                unsigned short bv = f2bf(v);
                if (sect < 2) lds[QK_OFF + sect * 2560 + row * 40 + cc] = bv;
                else          lds[VT_OFF + cc * 72 + row] = bv;
            }
        }
        __syncthreads();   // B2: q,k,v visible cross-wave

        // ======== Phase B: prefetch proj frags + bias values, then scores ========
        s8v pb[6];
        const s8v* pp = ppack_g + (size_t)h * (24 * 64) + l;
#pragma unroll
        for (int j = 0; j < 6; ++j) pb[j] = pp[(w * 6 + j) * 64];

        float bvv[4][4];
        const char* rpbb = (const char*)rpb + h * 4;
#pragma unroll
        for (int nt = 0; nt < 4; ++nt)
#pragma unroll
            for (int reg = 0; reg < 4; ++reg) {
                int bo = boff[nt][reg];
                bvv[nt][reg] = *(const float*)(rpbb + (bo < 0 ? 0 : bo));
            }

        s8v qa = *(const s8v*)(&lds[QK_OFF + (w * 16 + l15) * 40 + lq * 8]);
        f4v sc[4];
#pragma unroll
        for (int nt = 0; nt < 4; ++nt) {
            s8v kb = *(const s8v*)(&lds[QK_OFF + 2560 + (nt * 16 + l15) * 40 + lq * 8]);
            sc[nt] = __builtin_amdgcn_mfma_f32_16x16x32_bf16(qa, kb, fz, 0, 0, 0);
        }
#pragma unroll
        for (int nt = 0; nt < 4; ++nt)
#pragma unroll
            for (int reg = 0; reg < 4; ++reg) {
                float v = sc[nt][reg] + bvv[nt][reg];
                sc[nt][reg] = (boff[nt][reg] < 0) ? -1e30f : v;
            }
#pragma unroll
        for (int reg = 0; reg < 4; ++reg) {
            float m = fmaxf(fmaxf(sc[0][reg], sc[1][reg]), fmaxf(sc[2][reg], sc[3][reg]));
            m = fmaxf(m, __shfl_xor(m, 1));
            m = fmaxf(m, __shfl_xor(m, 2));
            m = fmaxf(m, __shfl_xor(m, 4));
            m = fmaxf(m, __shfl_xor(m, 8));
            float e0 = __expf(sc[0][reg] - m);
            float e1 = __expf(sc[1][reg] - m);
            float e2 = __expf(sc[2][reg] - m);
            float e3 = __expf(sc[3][reg] - m);
            float t = (e0 + e1) + (e2 + e3);
            t += __shfl_xor(t, 1);
            t += __shfl_xor(t, 2);
            t += __shfl_xor(t, 4);
            t += __shfl_xor(t, 8);
            float inv = 1.0f / t;
            sc[0][reg] = e0 * inv; sc[1][reg] = e1 * inv;
            sc[2][reg] = e2 * inv; sc[3][reg] = e3 * inv;
        }
        // P -> PL (own rows only; same-wave round trip, no barrier needed)
#pragma unroll
        for (int nt = 0; nt < 4; ++nt)
#pragma unroll
            for (int reg = 0; reg < 4; ++reg) {
                int row = w * 16 + lq * 4 + reg;
                lds[PL_OFF + row * 72 + nt * 16 + l15] = f2bf(sc[nt][reg]);
            }

        // ======== Phase C: head_out = P @ V  (M=16/wave, N=32, K=64) ========
        f4v ho[2] = {fz, fz};
#pragma unroll
        for (int ks = 0; ks < 2; ++ks) {
            s8v pa = *(const s8v*)(&lds[PL_OFF + (w * 16 + l15) * 72 + ks * 32 + lq * 8]);
#pragma unroll
            for (int nt = 0; nt < 2; ++nt) {
                s8v vb = *(const s8v*)(&lds[VT_OFF + (nt * 16 + l15) * 72 + ks * 32 + lq * 8]);
                ho[nt] = __builtin_amdgcn_mfma_f32_16x16x32_bf16(pa, vb, ho[nt], 0, 0, 0);
            }
        }
        // ho -> PL cols [0,32) of own rows (data-dependence-safe; cross-wave via B3)
#pragma unroll
        for (int nt = 0; nt < 2; ++nt)
#pragma unroll
            for (int reg = 0; reg < 4; ++reg) {
                int row = w * 16 + lq * 4 + reg;
                lds[PL_OFF + row * 72 + nt * 16 + l15] = f2bf(ho[nt][reg]);
            }
        __syncthreads();   // B3: ho visible cross-wave

        // ======== Phase D: out += head_out @ proj_w[:, h*32:+32]^T ========
        s8v ha[4];
#pragma unroll
        for (int mt = 0; mt < 4; ++mt)
            ha[mt] = *(const s8v*)(&lds[PL_OFF + (mt * 16 + l15) * 72 + lq * 8]);
#pragma unroll
        for (int j = 0; j < 6; ++j) {
#pragma unroll
            for (int mt = 0; mt < 4; ++mt)
                oc[mt][j] = __builtin_amdgcn_mfma_f32_16x16x32_bf16(ha[mt], pb[j], oc[mt][j], 0, 0, 0);
        }
    }

    // ======== epilogue: + proj_b, non-temporal fp32 stores (rows < 49) ========
#pragma unroll
    for (int j = 0; j < 6; ++j) {
        int col = (w * 6 + j) * 16 + l15;
        float pbv = projb[col];
#pragma unroll
        for (int mt = 0; mt < 4; ++mt)
#pragma unroll
            for (int reg = 0; reg < 4; ++reg) {
                int row = mt * 16 + lq * 4 + reg;
                if (row < NTOK)
                    __builtin_nontemporal_store(
                        oc[mt][j][reg] + pbv,
                        &outg[(size_t)b * (NTOK * DIM) + row * DIM + col]);
            }
    }
}

extern "C" void kernel_launch(void* const* d_in, const int* in_sizes, int n_in,
                              void* d_out, int out_size, void* d_ws, size_t ws_size,
                              hipStream_t stream) {
    (void)n_in; (void)d_ws; (void)ws_size; (void)out_size;
    const int B = in_sizes[0] / (NTOK * DIM);   // in_sizes is ELEMENT count -> B = 2048
    hipLaunchKernelGGL(prepack, dim3((QFRAGS + PFRAGS) / 256), dim3(256), 0, stream,
        (const float*)d_in[2],     // qkv_w
        (const float*)d_in[4]);    // proj_w
    hipLaunchKernelGGL(winattn_fused, dim3(B), dim3(256), 0, stream,
        (const float*)        d_in[0],
        (const unsigned char*)d_in[1],
        (const float*)        d_in[3],   // qkv_b
        (const float*)        d_in[5],   // proj_b
        (const float*)        d_in[6],   // rpb_table
        (const int*)          d_in[7],   // rel_index
        (float*)              d_out);
}